// Round 6
// baseline (234.651 us; speedup 1.0000x reference)
//
#include <hip/hip_runtime.h>

// WeatherLSTM round 6: fat-wave variant — 4 waves/block, 4 M-tiles/wave.
//  - grid 256 x 256 thr (4 waves, 1/SIMD); block owns 16 samples.
//  - Wave w owns units w*16..w*16+15 as 4 M-tiles; row perm m = ul*4 + g.
//    Tile T covers units w*16 + (T>>1)*8 + 2*ul + (T&1)  (paired so each
//    thread's tile-pair h outputs pack into one ds_write_b32).
//  - R4/R5 single-barrier pipeline: iter k computes L0(k) and L1(k-1);
//    both consume the same h0(k-1) B-frags -> 5 ds_read_b128 per WAVE per
//    iter (was per-wave x16 waves in R5: 4x less LDS traffic per CU).
//  - Rationale (R5 post-mortem): per-SIMD trans issue (~896 cyc/iter at
//    ~16 cyc/trans-instr) is invariant; what shrinks is LDS redundancy,
//    per-wave loop overhead, and barrier skew. 8 independent act chains
//    per thread provide ILP at 1 wave/SIMD.
//  - x table [169][16][8 halves] = 43.3KB LDS (row 168 zeros; quads 1..3
//    broadcast-read quad0's row, their A-frag k64..95 is zero).
//  - Acts: weights prescaled log2e (2log2e for g); shared-rcp, fused
//    i*tanh(g). MFMA layouts per m89/m91/m120 (verified R2-R5: 4.88e-4).

typedef _Float16 h8 __attribute__((ext_vector_type(8)));
typedef _Float16 h4 __attribute__((ext_vector_type(4)));
typedef float f4 __attribute__((ext_vector_type(4)));

#define ROWB 208
#define HBUF (16 * ROWB)          // 3328 B per h buffer
#define XTAB_OFF 0
#define XTAB_BYTES (169 * 256)    // 43264 B (row 168 = zero pad)
#define H0_OFF XTAB_BYTES
#define H1_OFF (H0_OFF + 2 * HBUF)
#define SMEM_TOTAL (H1_OFF + 2 * HBUF)   // 56576 B

#define K1F 1.4426950408889634f   // log2(e)
#define K2F 2.8853900817779268f   // 2*log2(e)

__device__ __forceinline__ float exp2_(float x) {
#if __has_builtin(__builtin_amdgcn_exp2f)
  return __builtin_amdgcn_exp2f(x);
#else
  float r; asm("v_exp_f32 %0, %1" : "=v"(r) : "v"(x)); return r;
#endif
}
__device__ __forceinline__ float rcp_(float x) {
#if __has_builtin(__builtin_amdgcn_rcpf)
  return __builtin_amdgcn_rcpf(x);
#else
  float r; asm("v_rcp_f32 %0, %1" : "=v"(r) : "v"(x)); return r;
#endif
}

__device__ __forceinline__ f4 mfma16(h8 a, h8 b, f4 c) {
  return __builtin_amdgcn_mfma_f32_16x16x32_f16(a, b, c, 0, 0, 0);
}

__device__ __forceinline__ h8 load_w8s(const float* __restrict__ p, float sc) {
  h8 r;
#pragma unroll
  for (int j = 0; j < 8; j++) r[j] = (_Float16)(p[j] * sc);
  return r;
}

__device__ __forceinline__ unsigned packh2(float a, float b) {
  unsigned lo = (unsigned)__builtin_bit_cast(unsigned short, (_Float16)a);
  unsigned hi = (unsigned)__builtin_bit_cast(unsigned short, (_Float16)b);
  return lo | (hi << 16);
}

// a[0]=i,a[1]=f,a[3]=o prescaled K1F; a[2]=g prescaled K2F.
// sigm(i)*tanh(g) = B*D*(Eg-1)*R with R=1/(ABCD).
__device__ __forceinline__ void lstm_act(f4 a, float& c, float& h) {
  float Ei = exp2_(-a[0]);
  float Ef = exp2_(-a[1]);
  float Eg = exp2_(a[2]);
  float Eo = exp2_(-a[3]);
  float A = 1.f + Ei, B = 1.f + Ef, C = 1.f + Eg, D = 1.f + Eo;
  float AB = A * B, CD = C * D, BD = B * D;
  float R  = rcp_(AB * CD);
  float fv = (A * CD) * R;               // sigm(f)
  float ig = (BD * (Eg - 1.f)) * R;      // sigm(i)*tanh(g)
  float ov = (AB * C) * R;               // sigm(o)
  c = fv * c + ig;
  float r2 = rcp_(exp2_(c * K2F) + 1.f);
  h = ov * (1.f - 2.f * r2);
}

extern "C" __global__ void __launch_bounds__(256, 1)
weather_lstm_mfma6(const float* __restrict__ x,
                   const float* __restrict__ Wih0, const float* __restrict__ Whh0,
                   const float* __restrict__ bih0, const float* __restrict__ bhh0,
                   const float* __restrict__ Wih1, const float* __restrict__ Whh1,
                   const float* __restrict__ bih1, const float* __restrict__ bhh1,
                   const float* __restrict__ W1, const float* __restrict__ b1,
                   const float* __restrict__ W2, const float* __restrict__ b2,
                   float* __restrict__ out)
{
  __shared__ __align__(16) unsigned char smem[SMEM_TOTAL];
  const int tid  = threadIdx.x;
  const int lane = tid & 63;
  const int w    = tid >> 6;      // wave 0..3 -> units w*16..w*16+15
  const int col  = lane & 15;     // sample index (B-frag n / C col)
  const int quad = lane >> 4;     // 0..3
  const int sB   = blockIdx.x * 16;
  const int ub   = w * 16;        // unit base for this wave

  // ---- A-frag row decode: m = lane&15 = ul*4 + g ----
  const int g_  = col & 3;
  const int ul_ = col >> 2;
  const float asc = (g_ == 2) ? K2F : K1F;

  // ---- load + prescale weight A-frags (once): 4 tiles ----
  h8 a0[4][3], a1i[4][2], a1h[4][2];
#pragma unroll
  for (int T = 0; T < 4; T++) {
    const int unit = ub + (T >> 1) * 8 + 2 * ul_ + (T & 1);
    const int r = g_ * 64 + unit;
#pragma unroll
    for (int f = 0; f < 2; f++) {
      a0[T][f]  = load_w8s(Whh0 + r * 64 + f * 32 + quad * 8, asc);
      a1i[T][f] = load_w8s(Wih1 + r * 64 + f * 32 + quad * 8, asc);
      a1h[T][f] = load_w8s(Whh1 + r * 64 + f * 32 + quad * 8, asc);
    }
    h8 xw = {};
    if (quad == 0) {
#pragma unroll
      for (int j = 0; j < 4; j++) xw[j] = (_Float16)(Wih0[r * 4 + j] * asc);
    }
    a0[T][2] = xw;
  }

  // ---- biases (prescaled): C/D row reg -> gate reg, unit per tile/quad ----
  f4 bias0v[4], bias1v[4];
#pragma unroll
  for (int T = 0; T < 4; T++) {
#pragma unroll
    for (int reg = 0; reg < 4; reg++) {
      const int rr = reg * 64 + ub + (T >> 1) * 8 + 2 * quad + (T & 1);
      const float bs = (reg == 2) ? K2F : K1F;
      bias0v[T][reg] = (bih0[rr] + bhh0[rr]) * bs;
      bias1v[T][reg] = (bih1[rr] + bhh1[rr]) * bs;
    }
  }

  // ---- zero LDS, build x table ----
  for (int idx = tid; idx < SMEM_TOTAL / 4; idx += 256) ((int*)smem)[idx] = 0;
  __syncthreads();
  for (int idx = tid; idx < 16 * 168; idx += 256) {
    const int c_ = idx / 168, t_ = idx - c_ * 168;
    f4 xv = *(const f4*)(x + ((size_t)(sB + c_) * 168 + t_) * 4);
    h4 xh;
#pragma unroll
    for (int j = 0; j < 4; j++) xh[j] = (_Float16)xv[j];
    *(h4*)(smem + XTAB_OFF + t_ * 256 + c_ * 16) = xh;
  }
  __syncthreads();

  float c0[4] = {0.f, 0.f, 0.f, 0.f}, c1[4] = {0.f, 0.f, 0.f, 0.f};
  float hl[4] = {0.f, 0.f, 0.f, 0.f};
  const int bo  = col * ROWB + quad * 16;              // B-frag byte offset
  const int wo0 = col * ROWB + (ub + 2 * quad) * 2;    // tile-pair 0/1 write
  const int wo1 = wo0 + 16;                            // tile-pair 2/3 (+8 units)
  const unsigned char* xp = smem + XTAB_OFF + col * 16;

  for (int k = 0; k <= 168; k++) {
    const int kb = k & 1, kbn = kb ^ 1;
    const unsigned char* h0r = smem + H0_OFF + kbn * HBUF;  // h0(k-1)
    unsigned char*       h0w = smem + H0_OFF + kb  * HBUF;  // h0(k)
    const unsigned char* h1r = smem + H1_OFF + kb  * HBUF;  // h1(k-2)
    unsigned char*       h1w = smem + H1_OFF + kbn * HBUF;  // h1(k-1)

    // ---- 5 shared ds_reads per wave ----
    h8 b0  = *(const h8*)(h0r + bo);         // h0(k-1) k 0..31
    h8 b1v = *(const h8*)(h0r + bo + 64);    // h0(k-1) k 32..63
    h8 bx  = *(const h8*)(xp + k * 256);     // x(k) (quad0 data; others A=0)
    h8 q0  = *(const h8*)(h1r + bo);         // h1(k-2) k 0..31
    h8 q1  = *(const h8*)(h1r + bo + 64);    // h1(k-2) k 32..63

    // ---- 28 MFMAs, 8 independent chains ----
    f4 A[4], C[4];
#pragma unroll
    for (int T = 0; T < 4; T++) A[T] = mfma16(a0[T][0], b0, bias0v[T]);
#pragma unroll
    for (int T = 0; T < 4; T++) C[T] = mfma16(a1i[T][0], b0, bias1v[T]);
#pragma unroll
    for (int T = 0; T < 4; T++) A[T] = mfma16(a0[T][1], b1v, A[T]);
#pragma unroll
    for (int T = 0; T < 4; T++) C[T] = mfma16(a1i[T][1], b1v, C[T]);
#pragma unroll
    for (int T = 0; T < 4; T++) A[T] = mfma16(a0[T][2], bx, A[T]);
#pragma unroll
    for (int T = 0; T < 4; T++) C[T] = mfma16(a1h[T][0], q0, C[T]);
#pragma unroll
    for (int T = 0; T < 4; T++) C[T] = mfma16(a1h[T][1], q1, C[T]);

    // ---- L0 activations (discard at k==168) ----
    if (k < 168) {
      float h0o[4];
#pragma unroll
      for (int T = 0; T < 4; T++) lstm_act(A[T], c0[T], h0o[T]);
      *(unsigned*)(h0w + wo0) = packh2(h0o[0], h0o[1]);
      *(unsigned*)(h0w + wo1) = packh2(h0o[2], h0o[3]);
    }
    // ---- L1 activations (discard at k==0) ----
    if (k > 0) {
#pragma unroll
      for (int T = 0; T < 4; T++) lstm_act(C[T], c1[T], hl[T]);
      *(unsigned*)(h1w + wo0) = packh2(hl[0], hl[1]);
      *(unsigned*)(h1w + wo1) = packh2(hl[2], hl[3]);
    }
    __syncthreads();
  }

  // ---------- MLP head (x table region dead; overlay) ----------
  float* fh = (float*)smem;              // [16][64] final h2, fp32
#pragma unroll
  for (int T = 0; T < 4; T++)
    fh[col * 64 + (ub + (T >> 1) * 8 + 2 * quad + (T & 1))] = hl[T];
  __syncthreads();

  {
    const int u = tid & 63, grp = tid >> 6;  // 4 grps x 4 samples
    float za[4];
#pragma unroll
    for (int i = 0; i < 4; i++) za[i] = b1[u];
    const float* w1r = W1 + u * 64;
    for (int j = 0; j < 64; j++) {
      float wv = w1r[j];
#pragma unroll
      for (int i = 0; i < 4; i++) za[i] += wv * fh[(grp * 4 + i) * 64 + j];
    }
    float* zl = (float*)(smem + 4096);     // [16][64]
#pragma unroll
    for (int i = 0; i < 4; i++)
      zl[(grp * 4 + i) * 64 + u] = fmaxf(za[i], 0.f);
  }
  __syncthreads();

  if (tid < 192) {
    const float* zl = (const float*)(smem + 4096);
    const int s = tid / 12, o = tid - s * 12;
    float a = b2[o];
    for (int j = 0; j < 64; j++) a += W2[o * 64 + j] * zl[s * 64 + j];
    out[(sB + s) * 12 + o] = a;
  }
}

extern "C" void kernel_launch(void* const* d_in, const int* in_sizes, int n_in,
                              void* d_out, int out_size, void* d_ws, size_t ws_size,
                              hipStream_t stream) {
  (void)in_sizes; (void)n_in; (void)d_ws; (void)ws_size; (void)out_size;
  const float* x    = (const float*)d_in[0];
  const float* Wih0 = (const float*)d_in[1];
  const float* Whh0 = (const float*)d_in[2];
  const float* bih0 = (const float*)d_in[3];
  const float* bhh0 = (const float*)d_in[4];
  const float* Wih1 = (const float*)d_in[5];
  const float* Whh1 = (const float*)d_in[6];
  const float* bih1 = (const float*)d_in[7];
  const float* bhh1 = (const float*)d_in[8];
  const float* W1   = (const float*)d_in[9];
  const float* b1   = (const float*)d_in[10];
  const float* W2   = (const float*)d_in[11];
  const float* b2   = (const float*)d_in[12];

  weather_lstm_mfma6<<<dim3(256), dim3(256), 0, stream>>>(
      x, Wih0, Whh0, bih0, bhh0, Wih1, Whh1, bih1, bhh1, W1, b1, W2, b2,
      (float*)d_out);
}